// Round 21
// baseline (126.523 us; speedup 1.0000x reference)
//
#include <hip/hip_runtime.h>
#include <stdint.h>

// int4 grouped-quant GEMM: out[64][28672] = x[64][8192] . W^T + bias
// W packed [N][K/2] int32, one byte/int32 = 2 nibbles (low = even k), zp = 8,
// per-128-k scales. fp16 ref -> harness gives x/scales/bias/out as FP32.
// Round-21: SPLIT-K x2 on the R11+NT structure for resident-pipeline count.
// R19 best (97.3us) runs 1.75 blocks/CU; waits can't overlap. Now: grid 896
// (448 N-tiles x 2 K-halves), 48 KB LDS (32 W dbuf + 16 scales) -> 3 resident
// blocks/CU; X traffic UNCHANGED (each block reads only its K-half of xf);
// NT on W kept; counted vmcnt(8) never 0. Partials in d_ws + fixed-order
// reduce (+bias) kernel. Pre-commit: >=97us -> revert R19, declare roofline.

typedef __attribute__((ext_vector_type(8))) short     short8;
typedef __attribute__((ext_vector_type(4))) float     f32x4;
typedef __attribute__((ext_vector_type(4))) int       i32x4;
typedef __attribute__((ext_vector_type(2))) _Float16  f16x2;
typedef __attribute__((ext_vector_type(8))) _Float16  f16x8;

// async global->LDS, 16 B/lane; NT (CPol bit1) for the once-read W stream.
static __device__ __forceinline__ void gload_lds16_nt(const void* gp, void* lp) {
    __builtin_amdgcn_global_load_lds(
        (const __attribute__((address_space(1))) unsigned int*)gp,
        (__attribute__((address_space(3))) unsigned int*)lp, 16, 0, 2);
}

// int4 pair -> fp16 pair: u = 0x6400|nib (fp16 1024+v, exact), (u-1032) exact
// in f16 (= v-8), then *s (single rounding - matches reference fp16 mul).
static __device__ __forceinline__ f16x8 dequant(const i32x4& w, f16x2 s2) {
    const f16x2 c1032 = {(_Float16)1032.0f, (_Float16)1032.0f};
    union { unsigned u[4]; f16x8 v; } r;
    #pragma unroll
    for (int j = 0; j < 4; ++j) {
        unsigned v = (unsigned)w[j];
        unsigned u = ((v & 0xFu) | 0x64006400u) | ((v << 12) & 0xF0000u);
        f16x2 h = __builtin_bit_cast(f16x2, u);
        h = (h - c1032) * s2;
        r.u[j] = __builtin_bit_cast(unsigned, h);
    }
    return r.v;
}

// x fp32 [64][K] -> fp16 (lossless) in A-fragment order: xf[g][st][mt][lane][8]
__global__ __launch_bounds__(256)
void xpack_kernel(const float* __restrict__ x, unsigned short* __restrict__ xf, int K) {
    int c    = blockIdx.x * 256 + threadIdx.x;
    int g    = c >> 10;
    int st   = (c >> 8) & 3;
    int mt   = (c >> 6) & 3;
    int lane = c & 63;
    int quad = lane >> 4, l15 = lane & 15;
    const float* p = x + (size_t)(l15 + mt * 16) * K + g * 128 + st * 32 + quad * 8;
    f32x4 lo = *(const f32x4*)p;
    f32x4 hi = *(const f32x4*)(p + 4);
    f16x8 r = { (_Float16)lo[0], (_Float16)lo[1], (_Float16)lo[2], (_Float16)lo[3],
                (_Float16)hi[0], (_Float16)hi[1], (_Float16)hi[2], (_Float16)hi[3] };
    *(short8*)(xf + (size_t)c * 8) = __builtin_bit_cast(short8, r);
}

// out[i] = pbuf[0][i] + pbuf[1][i] + bias[i % N]  (fixed order, deterministic)
__global__ __launch_bounds__(256)
void reduce_kernel(const float* __restrict__ pbuf, const float* __restrict__ bias,
                   float* __restrict__ out, int N, int total) {
    int i = (blockIdx.x * 256 + threadIdx.x) * 4;
    if (i >= total) return;
    f32x4 a = *(const f32x4*)(pbuf + i);
    f32x4 b = *(const f32x4*)(pbuf + (size_t)total + i);
    f32x4 bb = *(const f32x4*)(bias + (i % N));
    *(f32x4*)(out + i) = (a + b) + bb;
}

// bias == nullptr: write fp32 partial to dst + ks*64*N (split path).
// bias != nullptr: single split, add bias, write final.
__global__ __launch_bounds__(256, 3)
void int4mm_kernel(const unsigned short* __restrict__ xf,  // fp16 frag-ordered x
                   const int*   __restrict__ wp,           // [N][K/2]
                   const float* __restrict__ sc,           // [N][ng]
                   const float* __restrict__ bias,         // [N] or nullptr
                   float*       __restrict__ dst,
                   int K, int N, int nsplit)
{
    __shared__ char lds[49152];              // 32 KB W dbuf | 16 KB scales
    char*  ldsW = lds;                       // [2][64 col][16 slot][16 B]
    float* ldsS = (float*)(lds + 32768);     // [gps][64 col]
    // (epilogue reuses ldsW+ for cross-wave partials, 48 KB)

    const int tid  = threadIdx.x;
    const int lane = tid & 63;
    const int wave = tid >> 6;               // kstep owner: k-quarter of each group
    const int quad = lane >> 4;
    const int l15  = lane & 15;
    const int ng   = K / 128;                // 64 groups total
    const int gps  = ng / nsplit;            // groups this block (32 or 64)
    const int bid  = blockIdx.x;
    const int ntile = bid / nsplit;
    const int ks    = bid - ntile * nsplit;
    const int blk64 = ntile * 64;
    const int g0    = ks * gps;

    const char* wp8 = (const char*)wp;       // one col's W row = 16384 B

    // W stage sources (R11-verified involution): instr j covers cols
    // wave*16 + j*4 + quad; lane supplies global chunk l15^(j*4+quad);
    // LDS slot s of col c ends up holding chunk s^(c&15). g0 folded in.
    unsigned woff[4];
    #pragma unroll
    for (int j = 0; j < 4; ++j) {
        const int cloc  = wave * 16 + j * 4 + quad;
        const int chunk = l15 ^ (j * 4 + quad);
        woff[j] = ((unsigned)(blk64 + cloc) << 14) + ((unsigned)chunk << 4)
                + (unsigned)g0 * 256;
    }

    // B-frag ds_read: col c = nt*16+l15, chunk q = wave*4+quad at slot q^l15.
    const int q = wave * 4 + quad;
    int rdW[4];
    #pragma unroll
    for (int nt = 0; nt < 4; ++nt)
        rdW[nt] = (nt * 16 + l15) * 256 + ((q ^ l15) << 4);

    // ---- prologue ----
    // scales: ldsS[g][c] = sc[(blk64+c)*ng + g0 + g], g in [0,gps).
    {
        const int c   = tid & 63;
        const int gg0 = (tid >> 6) * (gps >> 2);     // gps/4 groups per wave-row
        const float* sp = sc + (size_t)(blk64 + c) * ng + g0 + gg0;
        #pragma unroll
        for (int b = 0; b < 4; ++b) {                // up to 4 f32x4 (16 groups)
            if (b < (gps >> 4) || (b == 0)) {        // gps=32 -> 2; gps=64 -> 4
            }
        }
        const int nb = gps >> 4;                     // 2 or 4
        for (int b = 0; b < nb; ++b) {
            f32x4 s = *(const f32x4*)(sp + b * 4);
            #pragma unroll
            for (int j = 0; j < 4; ++j)
                ldsS[(gg0 + b * 4 + j) * 64 + c] = s[j];
        }
    }
    #pragma unroll
    for (int j = 0; j < 4; ++j)              // stage W(g0) -> buf0 (NT)
        gload_lds16_nt(wp8 + woff[j], ldsW + (wave * 4 + j) * 1024);

    const char* xbase = (const char*)xf + wave * 4096 + lane * 16;
    f16x8 xn[4], xc[4];
    #pragma unroll
    for (int mt = 0; mt < 4; ++mt)           // X(g0) -> regs
        xn[mt] = *(const f16x8*)(xbase + (size_t)g0 * 16384 + mt * 1024);

    f32x4 acc[4][4];
    #pragma unroll
    for (int mt = 0; mt < 4; ++mt)
        #pragma unroll
        for (int nt = 0; nt < 4; ++nt)
            acc[mt][nt] = f32x4{0.f, 0.f, 0.f, 0.f};

    __syncthreads();   // prologue drain: scales + W + X landed

    // Main loop. Per-iter VMEM = 4 X + 4 W = 8, fenced between the memory-
    // clobber asms. vmcnt(8): the 8 newest {X(g+1), W(g+1)} stay in flight;
    // W(g) (issued last iter) is forced complete by in-order retirement.
    #pragma unroll 1
    for (int g = 0; g < gps; ++g) {
        const int p  = g & 1;
        const int gn = (g + 1 < gps) ? g + 1 : gps - 1;  // clamped dead tail

        #pragma unroll
        for (int mt = 0; mt < 4; ++mt) xc[mt] = xn[mt];  // consume X(g)
        const char* xs = xbase + (size_t)(g0 + gn) * 16384;  // issue X(g+1)
        #pragma unroll
        for (int mt = 0; mt < 4; ++mt)
            xn[mt] = *(const f16x8*)(xs + mt * 1024);

        __builtin_amdgcn_s_barrier();        // iter g-1 readers of buf[p^1] done

        #pragma unroll
        for (int j = 0; j < 4; ++j)          // stage W(g+1) -> buf[p^1] (NT)
            gload_lds16_nt(wp8 + woff[j] + (size_t)gn * 256,
                           ldsW + (p ^ 1) * 16384 + (wave * 4 + j) * 1024);

        asm volatile("s_waitcnt vmcnt(8)" ::: "memory");  // W(g) landed (mine)
        __builtin_amdgcn_s_barrier();                     // ...for all waves
        __builtin_amdgcn_sched_barrier(0);   // keep ds_reads below the sync

        const char* wb = ldsW + p * 16384;
        const float* sg = ldsS + g * 64;
        const float sf0 = sg[l15], sf1 = sg[16 + l15];
        const float sf2 = sg[32 + l15], sf3 = sg[48 + l15];

        i32x4 v0 = *(const i32x4*)(wb + rdW[0]);
        i32x4 v1 = *(const i32x4*)(wb + rdW[1]);
        i32x4 v2 = *(const i32x4*)(wb + rdW[2]);
        i32x4 v3 = *(const i32x4*)(wb + rdW[3]);

        {
            f16x8 b = dequant(v0, f16x2{(_Float16)sf0, (_Float16)sf0});
            #pragma unroll
            for (int mt = 0; mt < 4; ++mt)
                acc[mt][0] = __builtin_amdgcn_mfma_f32_16x16x32_f16(xc[mt], b, acc[mt][0], 0, 0, 0);
        }
        {
            f16x8 b = dequant(v1, f16x2{(_Float16)sf1, (_Float16)sf1});
            #pragma unroll
            for (int mt = 0; mt < 4; ++mt)
                acc[mt][1] = __builtin_amdgcn_mfma_f32_16x16x32_f16(xc[mt], b, acc[mt][1], 0, 0, 0);
        }
        {
            f16x8 b = dequant(v2, f16x2{(_Float16)sf2, (_Float16)sf2});
            #pragma unroll
            for (int mt = 0; mt < 4; ++mt)
                acc[mt][2] = __builtin_amdgcn_mfma_f32_16x16x32_f16(xc[mt], b, acc[mt][2], 0, 0, 0);
        }
        {
            f16x8 b = dequant(v3, f16x2{(_Float16)sf3, (_Float16)sf3});
            #pragma unroll
            for (int mt = 0; mt < 4; ++mt)
                acc[mt][3] = __builtin_amdgcn_mfma_f32_16x16x32_f16(xc[mt], b, acc[mt][3], 0, 0, 0);
        }
    }

    // ---- epilogue: cross-wave (kstep) reduce. Wave w owns mt = w. ----
    // Partials: addr(owner o, slot s, nt) = ((o*3+s)*4+nt)*1024 + lane*16 (48 KB).
    __syncthreads();
    #pragma unroll
    for (int o = 0; o < 4; ++o) {
        if (o == wave) continue;             // wave-uniform branch
        const int s = wave - (wave > o ? 1 : 0);
        #pragma unroll
        for (int nt = 0; nt < 4; ++nt)
            *(f32x4*)(lds + (size_t)(((o * 3 + s) * 4 + nt) * 1024) + lane * 16)
                = acc[o][nt];
    }
    __syncthreads();

    f32x4 own[4];
    #pragma unroll
    for (int nt = 0; nt < 4; ++nt) own[nt] = acc[0][nt];
    #pragma unroll
    for (int o = 1; o < 4; ++o)
        if (wave == o) {                     // wave-uniform, compile-time acc idx
            own[0] = acc[o][0]; own[1] = acc[o][1];
            own[2] = acc[o][2]; own[3] = acc[o][3];
        }
    #pragma unroll
    for (int s = 0; s < 3; ++s)
        #pragma unroll
        for (int nt = 0; nt < 4; ++nt)
            own[nt] += *(const f32x4*)(lds + (size_t)(((wave * 3 + s) * 4 + nt) * 1024)
                                       + lane * 16);

    float* obase = dst + (size_t)ks * 64 * N;
    #pragma unroll
    for (int nt = 0; nt < 4; ++nt) {
        const int col = blk64 + nt * 16 + l15;
        const float bv = bias ? bias[col] : 0.0f;
        #pragma unroll
        for (int r = 0; r < 4; ++r)
            obase[(size_t)(wave * 16 + quad * 4 + r) * N + col] = own[nt][r] + bv;
    }
}

extern "C" void kernel_launch(void* const* d_in, const int* in_sizes, int n_in,
                              void* d_out, int out_size, void* d_ws, size_t ws_size,
                              hipStream_t stream)
{
    const float* x    = (const float*)d_in[0];
    const int*   wp   = (const int*)d_in[1];
    const float* sc   = (const float*)d_in[2];
    const float* bias = (const float*)d_in[3];
    float*       out  = (float*)d_out;

    const int N  = in_sizes[3];                       // 28672
    const long long Kh = (long long)in_sizes[1] / N;  // 4096
    const int K  = (int)(2 * Kh);                     // 8192
    const int ng = K / 128;                           // 64

    unsigned short* xf = (unsigned short*)d_ws;       // 1 MB frag-ordered fp16 x
    const size_t xf_bytes = (size_t)ng * 16384;
    const int    total    = 64 * N;
    const size_t need     = xf_bytes + 2ull * total * 4ull;

    xpack_kernel<<<(ng * 1024) / 256, 256, 0, stream>>>(x, xf, K);

    if (ws_size >= need && (ng & 31) == 0) {
        // split-K x2: 896 blocks (~3 resident/CU), partials + reduce.
        float* pbuf = (float*)((char*)d_ws + xf_bytes);
        int4mm_kernel<<<(N / 64) * 2, 256, 0, stream>>>(xf, wp, sc, nullptr, pbuf,
                                                        K, N, 2);
        reduce_kernel<<<(total / 4 + 255) / 256, 256, 0, stream>>>(pbuf, bias, out,
                                                                   N, total);
    } else {
        // fallback: single split (R11+NT path)
        int4mm_kernel<<<N / 64, 256, 0, stream>>>(xf, wp, sc, bias, out, K, N, 1);
    }
}

// Round 22
// 97.831 us; speedup vs baseline: 1.2933x; 1.2933x over previous
//
#include <hip/hip_runtime.h>
#include <stdint.h>

// int4 grouped-quant GEMM: out[64][28672] = x[64][8192] . W^T + bias
// W packed [N][K/2] int32, one byte/int32 = 2 nibbles (low = even k), zp = 8,
// per-128-k scales. fp16 ref -> harness gives x/scales/bias/out as FP32.
// FINAL (revert to Round-19 best, 97.3 us): R14 structure (superstep-2 W
// staging, kstep-split waves, X-in-regs, involution-swizzled global_load_lds,
// counted vmcnt never 0) + NONTEMPORAL cache policy on the W DMA (the 470 MB
// once-read stream no longer thrashes the per-XCD L2). 4.85 TB/s effective
// on the weight stream = 77% of sequential-copy ceiling; all CU pipes <15%
// busy; 15 scheduling/layout/occupancy variants tested, none exceeded this.

typedef __attribute__((ext_vector_type(8))) short     short8;
typedef __attribute__((ext_vector_type(4))) float     f32x4;
typedef __attribute__((ext_vector_type(4))) int       i32x4;
typedef __attribute__((ext_vector_type(2))) _Float16  f16x2;
typedef __attribute__((ext_vector_type(8))) _Float16  f16x8;

// async global->LDS, 16 B/lane, default policy (cached) — for X-like data.
static __device__ __forceinline__ void gload_lds16(const void* gp, void* lp) {
    __builtin_amdgcn_global_load_lds(
        (const __attribute__((address_space(1))) unsigned int*)gp,
        (__attribute__((address_space(3))) unsigned int*)lp, 16, 0, 0);
}
// nontemporal variant (CPol NT bit, gfx9: 1<<1) — for the once-read W stream.
static __device__ __forceinline__ void gload_lds16_nt(const void* gp, void* lp) {
    __builtin_amdgcn_global_load_lds(
        (const __attribute__((address_space(1))) unsigned int*)gp,
        (__attribute__((address_space(3))) unsigned int*)lp, 16, 0, 2);
}

// int4 pair -> fp16 pair: u = 0x6400|nib (fp16 1024+v, exact), (u-1032) exact
// in f16 (= v-8), then *s (single rounding - matches reference fp16 mul).
static __device__ __forceinline__ f16x8 dequant(const i32x4& w, f16x2 s2) {
    const f16x2 c1032 = {(_Float16)1032.0f, (_Float16)1032.0f};
    union { unsigned u[4]; f16x8 v; } r;
    #pragma unroll
    for (int j = 0; j < 4; ++j) {
        unsigned v = (unsigned)w[j];
        unsigned u = ((v & 0xFu) | 0x64006400u) | ((v << 12) & 0xF0000u);
        f16x2 h = __builtin_bit_cast(f16x2, u);
        h = (h - c1032) * s2;
        r.u[j] = __builtin_bit_cast(unsigned, h);
    }
    return r.v;
}

// x fp32 [64][K] -> fp16 (lossless) in A-fragment order: xf[g][st][mt][lane][8]
__global__ __launch_bounds__(256)
void xpack_kernel(const float* __restrict__ x, unsigned short* __restrict__ xf, int K) {
    int c    = blockIdx.x * 256 + threadIdx.x;
    int g    = c >> 10;
    int st   = (c >> 8) & 3;
    int mt   = (c >> 6) & 3;
    int lane = c & 63;
    int quad = lane >> 4, l15 = lane & 15;
    const float* p = x + (size_t)(l15 + mt * 16) * K + g * 128 + st * 32 + quad * 8;
    f32x4 lo = *(const f32x4*)p;
    f32x4 hi = *(const f32x4*)(p + 4);
    f16x8 r = { (_Float16)lo[0], (_Float16)lo[1], (_Float16)lo[2], (_Float16)lo[3],
                (_Float16)hi[0], (_Float16)hi[1], (_Float16)hi[2], (_Float16)hi[3] };
    *(short8*)(xf + (size_t)c * 8) = __builtin_bit_cast(short8, r);
}

__global__ __launch_bounds__(256, 2)
void int4mm_kernel(const unsigned short* __restrict__ xf,  // fp16 frag-ordered x
                   const int*   __restrict__ wp,           // [N][K/2]
                   const float* __restrict__ sc,           // [N][ng]
                   const float* __restrict__ bias,         // [N]
                   float*       __restrict__ out,          // [64][N]
                   int K, int N)
{
    __shared__ char lds[81920];              // 64 KB W dbuf | 16 KB scales
    char*  ldsW = lds;                       // [2][64 col][32 slot][16 B]
    float* ldsS = (float*)(lds + 65536);     // [64 g][64 col]
    // (epilogue reuses ldsW for cross-wave partials, 48 KB)

    const int tid  = threadIdx.x;
    const int lane = tid & 63;
    const int wave = tid >> 6;               // kstep owner: k-quarter of each group
    const int quad = lane >> 4;
    const int l15  = lane & 15;
    const int blk64 = blockIdx.x * 64;
    const int ng   = K / 128;                // 64 groups
    const int ns   = ng / 2;                 // 32 supersteps (2 groups each)

    const char* wp8 = (const char*)wp;       // one col's W row = 16384 B

    // W stage sources (superstep = 512 B/col, 32 chunks): stage instr j of
    // wave w covers cols (w*8+j)*2 + (lane>>5); lane supplies global chunk
    // (lane&31) ^ (col&31); LDS slot t of col c holds chunk t ^ (c&31).
    unsigned woff[8];
    #pragma unroll
    for (int j = 0; j < 8; ++j) {
        const int cloc  = (wave * 8 + j) * 2 + (lane >> 5);
        const int chunk = (lane & 31) ^ (cloc & 31);
        woff[j] = ((unsigned)(blk64 + cloc) << 14) + ((unsigned)chunk << 4);
    }

    // B-frag ds_read offsets: col = nt*16+l15 (byte base col*512); group
    // parity e chunk = e*16 + q (q = wave*4+quad), stored at slot
    // (e^(nt&1))*16 + (q^l15) -> same verified 8-beat-optimal family.
    const int q = wave * 4 + quad;
    int rdA[4], rdB[4];
    #pragma unroll
    for (int nt = 0; nt < 4; ++nt) {
        const int base = (nt * 16 + l15) * 512 + ((q ^ l15) << 4);
        rdA[nt] = base + (((0 ^ (nt & 1)) * 16) << 4);
        rdB[nt] = base + (((1 ^ (nt & 1)) * 16) << 4);
    }

    // ---- prologue ----
    // scales: ldsS[g][c] = sc[(blk64+c)*ng + g] via 64 B contiguous loads.
    {
        const int c  = tid & 63;
        const int g0 = (tid >> 6) * 16;
        const float* sp = sc + (size_t)(blk64 + c) * ng + g0;
        f32x4 s0 = *(const f32x4*)(sp);
        f32x4 s1 = *(const f32x4*)(sp + 4);
        f32x4 s2 = *(const f32x4*)(sp + 8);
        f32x4 s3 = *(const f32x4*)(sp + 12);
        #pragma unroll
        for (int j = 0; j < 4; ++j) {
            ldsS[(g0 + 0  + j) * 64 + c] = s0[j];
            ldsS[(g0 + 4  + j) * 64 + c] = s1[j];
            ldsS[(g0 + 8  + j) * 64 + c] = s2[j];
            ldsS[(g0 + 12 + j) * 64 + c] = s3[j];
        }
    }
    #pragma unroll
    for (int j = 0; j < 8; ++j)              // stage W superstep 0 -> buf0 (NT)
        gload_lds16_nt(wp8 + woff[j], ldsW + (wave * 8 + j) * 1024);

    const char* xbase = (const char*)xf + wave * 4096 + lane * 16;
    f16x8 xa[4], xb[4];
    #pragma unroll
    for (int mt = 0; mt < 4; ++mt)           // X(0), X(1) -> regs
        xa[mt] = *(const f16x8*)(xbase + mt * 1024);
    #pragma unroll
    for (int mt = 0; mt < 4; ++mt)
        xb[mt] = *(const f16x8*)(xbase + 16384 + mt * 1024);

    f32x4 acc[4][4];
    #pragma unroll
    for (int mt = 0; mt < 4; ++mt)
        #pragma unroll
        for (int nt = 0; nt < 4; ++nt)
            acc[mt][nt] = f32x4{0.f, 0.f, 0.f, 0.f};

    __syncthreads();   // prologue drain: scales + W(S0) + X(0,1) landed

    // Main loop over supersteps. Per-iter VMEM = 8 W stages + 4 xa + 4 xb = 16.
    // vmcnt(16) leaves {xa(2s), xb(2s+1), W(s+1)} (the 16 newest) in flight
    // and forces W(s) — issued one full superstep (~2 group-periods) ago —
    // complete. X regs are additionally guarded by the compiler's own waits.
    #pragma unroll 1
    for (int s = 0; s < ns; ++s) {
        const int p  = s & 1;
        const int sn = (s + 1 < ns) ? s + 1 : ns - 1;   // clamped dead tail
        const int gA = 2 * s, gB = 2 * s + 1;
        const int nA = (gA + 2 < ng) ? gA + 2 : ng - 1; // X prefetch targets
        const int nB = (gB + 2 < ng) ? gB + 2 : ng - 1;

        __builtin_amdgcn_s_barrier();        // superstep s-1 readers of buf[p^1] done

        #pragma unroll
        for (int j = 0; j < 8; ++j)          // stage W(s+1) -> buf[p^1] (NT)
            gload_lds16_nt(wp8 + woff[j] + (size_t)sn * 512,
                           ldsW + (p ^ 1) * 32768 + (wave * 8 + j) * 1024);

        asm volatile("s_waitcnt vmcnt(16)" ::: "memory");  // W(s) landed (mine)
        __builtin_amdgcn_s_barrier();                      // ...for all waves
        __builtin_amdgcn_sched_barrier(0);   // keep ds_reads below the sync

        const char* wb = ldsW + p * 32768;
        const float* sgA = ldsS + gA * 64;
        const float* sgB = ldsS + gB * 64;

        {   // group A = 2s (fragments xa)
            i32x4 v0 = *(const i32x4*)(wb + rdA[0]);
            i32x4 v1 = *(const i32x4*)(wb + rdA[1]);
            i32x4 v2 = *(const i32x4*)(wb + rdA[2]);
            i32x4 v3 = *(const i32x4*)(wb + rdA[3]);
            const float sf0 = sgA[l15], sf1 = sgA[16 + l15];
            const float sf2 = sgA[32 + l15], sf3 = sgA[48 + l15];
            f16x8 b0 = dequant(v0, f16x2{(_Float16)sf0, (_Float16)sf0});
            f16x8 b1 = dequant(v1, f16x2{(_Float16)sf1, (_Float16)sf1});
            f16x8 b2 = dequant(v2, f16x2{(_Float16)sf2, (_Float16)sf2});
            f16x8 b3 = dequant(v3, f16x2{(_Float16)sf3, (_Float16)sf3});
            #pragma unroll
            for (int mt = 0; mt < 4; ++mt) {
                acc[mt][0] = __builtin_amdgcn_mfma_f32_16x16x32_f16(xa[mt], b0, acc[mt][0], 0, 0, 0);
                acc[mt][1] = __builtin_amdgcn_mfma_f32_16x16x32_f16(xa[mt], b1, acc[mt][1], 0, 0, 0);
                acc[mt][2] = __builtin_amdgcn_mfma_f32_16x16x32_f16(xa[mt], b2, acc[mt][2], 0, 0, 0);
                acc[mt][3] = __builtin_amdgcn_mfma_f32_16x16x32_f16(xa[mt], b3, acc[mt][3], 0, 0, 0);
            }
            const char* xs = xbase + (size_t)nA * 16384;   // issue X(2s+2)
            #pragma unroll
            for (int mt = 0; mt < 4; ++mt)
                xa[mt] = *(const f16x8*)(xs + mt * 1024);
        }
        {   // group B = 2s+1 (fragments xb)
            i32x4 v0 = *(const i32x4*)(wb + rdB[0]);
            i32x4 v1 = *(const i32x4*)(wb + rdB[1]);
            i32x4 v2 = *(const i32x4*)(wb + rdB[2]);
            i32x4 v3 = *(const i32x4*)(wb + rdB[3]);
            const float sf0 = sgB[l15], sf1 = sgB[16 + l15];
            const float sf2 = sgB[32 + l15], sf3 = sgB[48 + l15];
            f16x8 b0 = dequant(v0, f16x2{(_Float16)sf0, (_Float16)sf0});
            f16x8 b1 = dequant(v1, f16x2{(_Float16)sf1, (_Float16)sf1});
            f16x8 b2 = dequant(v2, f16x2{(_Float16)sf2, (_Float16)sf2});
            f16x8 b3 = dequant(v3, f16x2{(_Float16)sf3, (_Float16)sf3});
            #pragma unroll
            for (int mt = 0; mt < 4; ++mt) {
                acc[mt][0] = __builtin_amdgcn_mfma_f32_16x16x32_f16(xb[mt], b0, acc[mt][0], 0, 0, 0);
                acc[mt][1] = __builtin_amdgcn_mfma_f32_16x16x32_f16(xb[mt], b1, acc[mt][1], 0, 0, 0);
                acc[mt][2] = __builtin_amdgcn_mfma_f32_16x16x32_f16(xb[mt], b2, acc[mt][2], 0, 0, 0);
                acc[mt][3] = __builtin_amdgcn_mfma_f32_16x16x32_f16(xb[mt], b3, acc[mt][3], 0, 0, 0);
            }
            const char* xs = xbase + (size_t)nB * 16384;   // issue X(2s+3)
            #pragma unroll
            for (int mt = 0; mt < 4; ++mt)
                xb[mt] = *(const f16x8*)(xs + mt * 1024);
        }
    }

    // ---- epilogue: cross-wave (kstep) reduce. Wave w owns mt = w. ----
    // Partials: addr(owner o, slot s, nt) = ((o*3+s)*4+nt)*1024 + lane*16 (48 KB).
    __syncthreads();
    #pragma unroll
    for (int o = 0; o < 4; ++o) {
        if (o == wave) continue;             // wave-uniform branch
        const int s = wave - (wave > o ? 1 : 0);
        #pragma unroll
        for (int nt = 0; nt < 4; ++nt)
            *(f32x4*)(lds + (size_t)(((o * 3 + s) * 4 + nt) * 1024) + lane * 16)
                = acc[o][nt];
    }
    __syncthreads();

    f32x4 own[4];
    #pragma unroll
    for (int nt = 0; nt < 4; ++nt) own[nt] = acc[0][nt];
    #pragma unroll
    for (int o = 1; o < 4; ++o)
        if (wave == o) {                     // wave-uniform, compile-time acc idx
            own[0] = acc[o][0]; own[1] = acc[o][1];
            own[2] = acc[o][2]; own[3] = acc[o][3];
        }
    #pragma unroll
    for (int s = 0; s < 3; ++s)
        #pragma unroll
        for (int nt = 0; nt < 4; ++nt)
            own[nt] += *(const f32x4*)(lds + (size_t)(((wave * 3 + s) * 4 + nt) * 1024)
                                       + lane * 16);

    #pragma unroll
    for (int nt = 0; nt < 4; ++nt) {
        const int col = blk64 + nt * 16 + l15;
        const float bv = bias[col];
        #pragma unroll
        for (int r = 0; r < 4; ++r)
            out[(size_t)(wave * 16 + quad * 4 + r) * N + col] = own[nt][r] + bv;
    }
}

extern "C" void kernel_launch(void* const* d_in, const int* in_sizes, int n_in,
                              void* d_out, int out_size, void* d_ws, size_t ws_size,
                              hipStream_t stream)
{
    const float* x    = (const float*)d_in[0];
    const int*   wp   = (const int*)d_in[1];
    const float* sc   = (const float*)d_in[2];
    const float* bias = (const float*)d_in[3];
    float*       out  = (float*)d_out;

    const int N  = in_sizes[3];                       // 28672
    const long long Kh = (long long)in_sizes[1] / N;  // 4096
    const int K  = (int)(2 * Kh);                     // 8192
    const int ng = K / 128;                           // 64

    unsigned short* xf = (unsigned short*)d_ws;       // 1 MB frag-ordered fp16 x

    xpack_kernel<<<(ng * 1024) / 256, 256, 0, stream>>>(x, xf, K);
    int4mm_kernel<<<N / 64, 256, 0, stream>>>(xf, wp, sc, bias, out, K, N);
}